// Round 1
// baseline (911.779 us; speedup 1.0000x reference)
//
#include <hip/hip_runtime.h>
#include <hip/hip_bf16.h>
#include <math.h>

// ---------------- problem constants ----------------
#define BROWS      16384
#define NIN        256
#define ADIM       16
#define H0DIM      1024
#define H1DIM      1024
#define KBINS      128
#define NPARAM     385          // 383 spline params + wa-dot + wb-dot
#define NPAD       512          // padded N for gemm3
#define LN_EPS_F   1e-5f
#define MINW       0.001f
#define MINH       0.001f
#define MIND       0.001f

// ---------------- fp32 register-tiled GEMM ----------------
// C[M,N] = A[M,K] @ W[N,K]^T + bias[N]
// BM=BN=128, BK=16, 256 threads, 8x8 microtile per thread.
__global__ __launch_bounds__(256)
void gemm_bias_f32(const float* __restrict__ A, int lda,
                   const float* __restrict__ W, int ldw,
                   const float* __restrict__ bias,
                   float* __restrict__ C, int ldc,
                   int K, int Nstore)
{
    __shared__ float As[16][132];   // [k][m], pad 132: float4-aligned, bank-spread
    __shared__ float Ws[16][132];   // [k][n]

    const int tid = threadIdx.x;
    const int bm0 = blockIdx.x * 128;
    const int bn0 = blockIdx.y * 128;
    const int tm = tid & 15;        // 0..15
    const int tn = tid >> 4;        // 0..15
    const int lr = tid >> 2;        // 0..63 (staging row)
    const int lc = (tid & 3) * 4;   // 0,4,8,12 (staging col)

    float acc[8][8];
    #pragma unroll
    for (int i = 0; i < 8; ++i)
        #pragma unroll
        for (int j = 0; j < 8; ++j) acc[i][j] = 0.f;

    for (int k0 = 0; k0 < K; k0 += 16) {
        // stage A tile (128 x 16) transposed
        #pragma unroll
        for (int h = 0; h < 2; ++h) {
            const int m = lr + h * 64;
            const float4 v = *(const float4*)(A + (size_t)(bm0 + m) * lda + k0 + lc);
            As[lc + 0][m] = v.x; As[lc + 1][m] = v.y;
            As[lc + 2][m] = v.z; As[lc + 3][m] = v.w;
        }
        // stage W tile (128 x 16) transposed
        #pragma unroll
        for (int h = 0; h < 2; ++h) {
            const int n = lr + h * 64;
            const float4 v = *(const float4*)(W + (size_t)(bn0 + n) * ldw + k0 + lc);
            Ws[lc + 0][n] = v.x; Ws[lc + 1][n] = v.y;
            Ws[lc + 2][n] = v.z; Ws[lc + 3][n] = v.w;
        }
        __syncthreads();

        #pragma unroll
        for (int k = 0; k < 16; ++k) {
            const float4 a0 = *(const float4*)&As[k][tm * 4];
            const float4 a1 = *(const float4*)&As[k][tm * 4 + 64];
            const float4 b0 = *(const float4*)&Ws[k][tn * 4];
            const float4 b1 = *(const float4*)&Ws[k][tn * 4 + 64];
            float av[8], bv[8];
            av[0]=a0.x; av[1]=a0.y; av[2]=a0.z; av[3]=a0.w;
            av[4]=a1.x; av[5]=a1.y; av[6]=a1.z; av[7]=a1.w;
            bv[0]=b0.x; bv[1]=b0.y; bv[2]=b0.z; bv[3]=b0.w;
            bv[4]=b1.x; bv[5]=b1.y; bv[6]=b1.z; bv[7]=b1.w;
            #pragma unroll
            for (int i = 0; i < 8; ++i)
                #pragma unroll
                for (int j = 0; j < 8; ++j)
                    acc[i][j] = fmaf(av[i], bv[j], acc[i][j]);
        }
        __syncthreads();
    }

    // epilogue: bias add + store
    #pragma unroll
    for (int i = 0; i < 8; ++i) {
        const int m = bm0 + ((i < 4) ? (tm * 4 + i) : (64 + tm * 4 + i - 4));
        #pragma unroll
        for (int j = 0; j < 8; ++j) {
            const int n = bn0 + ((j < 4) ? (tn * 4 + j) : (64 + tn * 4 + j - 4));
            if (n < Nstore)
                C[(size_t)m * ldc + n] = acc[i][j] + bias[n];
        }
    }
}

// ---------------- LayerNorm + ReLU (one block per row, 256 thr, N=1024) ----------------
__global__ __launch_bounds__(256)
void ln_relu_f32(const float* __restrict__ Y,
                 const float* __restrict__ g, const float* __restrict__ b,
                 float* __restrict__ X, int xstride,
                 const float* __restrict__ actions)   // may be null
{
    __shared__ float red[4];
    const int row = blockIdx.x;
    const int tid = threadIdx.x;
    const float* y = Y + (size_t)row * 1024;
    float* xo = X + (size_t)row * xstride;

    const float4 v = *(const float4*)(y + tid * 4);

    // mean
    float s = v.x + v.y + v.z + v.w;
    #pragma unroll
    for (int off = 32; off > 0; off >>= 1) s += __shfl_down(s, off, 64);
    if ((tid & 63) == 0) red[tid >> 6] = s;
    __syncthreads();
    const float mu = (red[0] + red[1] + red[2] + red[3]) * (1.f / 1024.f);
    __syncthreads();

    // variance
    const float d0 = v.x - mu, d1 = v.y - mu, d2 = v.z - mu, d3 = v.w - mu;
    float s2 = d0 * d0 + d1 * d1 + d2 * d2 + d3 * d3;
    #pragma unroll
    for (int off = 32; off > 0; off >>= 1) s2 += __shfl_down(s2, off, 64);
    if ((tid & 63) == 0) red[tid >> 6] = s2;
    __syncthreads();
    const float var = (red[0] + red[1] + red[2] + red[3]) * (1.f / 1024.f);
    const float inv = 1.0f / sqrtf(var + LN_EPS_F);

    float4 o;
    o.x = fmaxf(0.f, d0 * inv * g[tid * 4 + 0] + b[tid * 4 + 0]);
    o.y = fmaxf(0.f, d1 * inv * g[tid * 4 + 1] + b[tid * 4 + 1]);
    o.z = fmaxf(0.f, d2 * inv * g[tid * 4 + 2] + b[tid * 4 + 2]);
    o.w = fmaxf(0.f, d3 * inv * g[tid * 4 + 3] + b[tid * 4 + 3]);
    *(float4*)(xo + tid * 4) = o;

    if (actions != nullptr && tid < ADIM)
        xo[1024 + tid] = actions[(size_t)row * ADIM + tid];
}

// ---------------- build concatenated [wv; wa; wb; 0-pad] weight + bias ----------------
__global__ __launch_bounds__(256)
void build_wcat(const float* __restrict__ wv, const float* __restrict__ wa,
                const float* __restrict__ wb, const float* __restrict__ bv,
                const float* __restrict__ ba, const float* __restrict__ bb,
                float* __restrict__ wcat, float* __restrict__ bcat)
{
    const int idx = blockIdx.x * 256 + threadIdx.x;
    if (idx < NPAD * 1024) {
        const int n = idx >> 10, k = idx & 1023;
        float v;
        if      (n < 383)  v = wv[n * 1024 + k];
        else if (n == 383) v = wa[k];
        else if (n == 384) v = wb[k];
        else               v = 0.f;
        wcat[idx] = v;
    }
    if (idx < NPAD) {
        float v;
        if      (idx < 383)  v = bv[idx];
        else if (idx == 383) v = ba[0];
        else if (idx == 384) v = bb[0];
        else                 v = 0.f;
        bcat[idx] = v;
    }
}

// ---------------- spline kernel: one block (128 thr) per row ----------------
__device__ __forceinline__ float softplus_f(float x) {
    return (x > 20.f) ? x : log1pf(expf(x));
}

__global__ __launch_bounds__(128)
void spline_rq(const float* __restrict__ P,   // [B,385]
               float* __restrict__ Out)       // [B,128]
{
    __shared__ float s[128];
    __shared__ float cw[129];
    __shared__ float ch[129];
    __shared__ float Dv[129];

    const int r = blockIdx.x;
    const int t = threadIdx.x;              // 0..127
    const float* p = P + (size_t)r * NPARAM;

    const float wlog = p[t];
    const float hlog = p[128 + t];
    const float sa = expf(p[383]);
    const float sb = p[384];

    // ---- softmax(W) + scan -> cw ----
    s[t] = wlog; __syncthreads();
    #pragma unroll
    for (int off = 64; off > 0; off >>= 1) {
        if (t < off) s[t] = fmaxf(s[t], s[t + off]);
        __syncthreads();
    }
    const float wmax = s[0]; __syncthreads();
    const float we = expf(wlog - wmax);
    s[t] = we; __syncthreads();
    #pragma unroll
    for (int off = 64; off > 0; off >>= 1) {
        if (t < off) s[t] += s[t + off];
        __syncthreads();
    }
    const float wsum = s[0]; __syncthreads();
    const float Wv = MINW + (1.f - MINW * KBINS) * (we / wsum);
    s[t] = Wv; __syncthreads();
    for (int off = 1; off < 128; off <<= 1) {
        const float tv = (t >= off) ? s[t - off] : 0.f;
        __syncthreads();
        s[t] += tv;
        __syncthreads();
    }
    if (t == 0) cw[0] = 0.f;
    cw[t + 1] = (t == 127) ? 1.0f : s[t];
    __syncthreads();

    // ---- softmax(H) + scan -> ch (scaled) ----
    s[t] = hlog; __syncthreads();
    #pragma unroll
    for (int off = 64; off > 0; off >>= 1) {
        if (t < off) s[t] = fmaxf(s[t], s[t + off]);
        __syncthreads();
    }
    const float hmax = s[0]; __syncthreads();
    const float he = expf(hlog - hmax);
    s[t] = he; __syncthreads();
    #pragma unroll
    for (int off = 64; off > 0; off >>= 1) {
        if (t < off) s[t] += s[t + off];
        __syncthreads();
    }
    const float hsum = s[0]; __syncthreads();
    const float Hv = MINH + (1.f - MINH * KBINS) * (he / hsum);
    s[t] = Hv; __syncthreads();
    for (int off = 1; off < 128; off <<= 1) {
        const float tv = (t >= off) ? s[t - off] : 0.f;
        __syncthreads();
        s[t] += tv;
        __syncthreads();
    }
    if (t == 0) ch[0] = sb;                 // sa*0 + sb
    ch[t + 1] = sa * s[t] + sb;

    // ---- derivatives ----
    const float EDGE = logf(expf(1.0f - 0.001f) - 1.0f);
    if (t == 0) { Dv[0] = EDGE; Dv[128] = EDGE; }
    if (t < 127) Dv[t + 1] = MIND + softplus_f(p[256 + t]);
    __syncthreads();

    // ---- per-tau evaluation ----
    const float tau = ((float)t + 0.5f) * (1.f / KBINS);
    int bin = -1;
    for (int j = 0; j < 129; ++j) bin += (tau >= cw[j]) ? 1 : 0;

    const float icw = cw[bin];
    const float ibw = cw[bin + 1] - cw[bin];
    const float ich = ch[bin];
    const float ih  = ch[bin + 1] - ch[bin];
    const float idelta = ih / ibw;
    const float d0 = Dv[bin];
    const float d1 = Dv[bin + 1];
    const float theta = (tau - icw) / ibw;
    const float tom = theta * (1.f - theta);
    const float num = ih * (idelta * theta * theta + d0 * tom);
    const float den = idelta + (d0 + d1 - 2.f * idelta) * tom;
    Out[(size_t)r * KBINS + t] = ich + num / den;
}

// ---------------- launcher ----------------
extern "C" void kernel_launch(void* const* d_in, const int* in_sizes, int n_in,
                              void* d_out, int out_size, void* d_ws, size_t ws_size,
                              hipStream_t stream) {
    const float* inputs  = (const float*)d_in[0];
    const float* actions = (const float*)d_in[1];
    const float* w1      = (const float*)d_in[2];
    const float* b1      = (const float*)d_in[3];
    const float* ln1_g   = (const float*)d_in[4];
    const float* ln1_b   = (const float*)d_in[5];
    const float* w2      = (const float*)d_in[6];
    const float* b2      = (const float*)d_in[7];
    const float* ln2_g   = (const float*)d_in[8];
    const float* ln2_b   = (const float*)d_in[9];
    const float* wv      = (const float*)d_in[10];
    const float* bv      = (const float*)d_in[11];
    const float* wa      = (const float*)d_in[12];
    const float* ba      = (const float*)d_in[13];
    const float* wb      = (const float*)d_in[14];
    const float* bb      = (const float*)d_in[15];
    float* out = (float*)d_out;

    // workspace layout (floats)
    float* ws = (float*)d_ws;
    float* ws_y     = ws;                                   // B*1024
    float* ws_xcat  = ws_y    + (size_t)BROWS * 1024;       // B*1040 (x1||act, later x2)
    float* ws_param = ws_xcat + (size_t)BROWS * 1040;       // B*385
    float* ws_wcat  = ws_param + (size_t)BROWS * NPARAM;    // 512*1024
    float* ws_bcat  = ws_wcat + (size_t)NPAD * 1024;        // 512

    // 0) concatenated head weights
    build_wcat<<<(NPAD * 1024 + 255) / 256, 256, 0, stream>>>(
        wv, wa, wb, bv, ba, bb, ws_wcat, ws_bcat);

    // 1) y1 = inputs @ w1^T + b1
    gemm_bias_f32<<<dim3(BROWS / 128, H0DIM / 128), 256, 0, stream>>>(
        inputs, NIN, w1, NIN, b1, ws_y, H0DIM, NIN, H0DIM);

    // 2) x1cat = [relu(ln(y1)), actions]
    ln_relu_f32<<<BROWS, 256, 0, stream>>>(ws_y, ln1_g, ln1_b, ws_xcat, 1040, actions);

    // 3) y2 = x1cat @ w2^T + b2
    gemm_bias_f32<<<dim3(BROWS / 128, H1DIM / 128), 256, 0, stream>>>(
        ws_xcat, 1040, w2, 1040, b2, ws_y, H1DIM, 1040, H1DIM);

    // 4) x2 = relu(ln(y2))  (reuse xcat region, stride 1024)
    ln_relu_f32<<<BROWS, 256, 0, stream>>>(ws_y, ln2_g, ln2_b, ws_xcat, 1024, nullptr);

    // 5) param = x2 @ wcat^T + bcat   (N padded to 512, store 385)
    gemm_bias_f32<<<dim3(BROWS / 128, NPAD / 128), 256, 0, stream>>>(
        ws_xcat, 1024, ws_wcat, 1024, ws_bcat, ws_param, NPARAM, 1024, NPARAM);

    // 6) spline evaluation
    spline_rq<<<BROWS, 128, 0, stream>>>(ws_param, out);
}

// Round 2
// 489.374 us; speedup vs baseline: 1.8632x; 1.8632x over previous
//
#include <hip/hip_runtime.h>
#include <hip/hip_bf16.h>
#include <math.h>

// ---------------- problem constants ----------------
#define BROWS      16384
#define LN_EPS_F   1e-5f
#define MINW       0.001f
#define MINH       0.001f
#define MIND       0.001f
// float(np.log(np.exp(0.999) - 1.0))
#define EDGE_CONST_F 0.5397423505783211f

typedef __bf16 bf16x8 __attribute__((ext_vector_type(8)));
typedef float  f32x4  __attribute__((ext_vector_type(4)));

// fp32 -> bf16 RNE, and back, via bit ops (no header dependence)
__device__ __forceinline__ ushort f2bf(float x) {
    union { float f; unsigned u; } v; v.f = x;
    unsigned u = v.u;
    u += 0x7fffu + ((u >> 16) & 1u);
    return (ushort)(u >> 16);
}
__device__ __forceinline__ float bf2f(ushort h) {
    union { unsigned u; float f; } v; v.u = ((unsigned)h) << 16;
    return v.f;
}

// ==================================================================
// MFMA GEMM, split-precision bf16x3:  C = A @ B^T + bias
//   A planes: [M][Kpad] bf16 (hi,lo)   B planes: [N][Kpad] bf16 (hi,lo)
//   128x128 tile, BK=32, 4 waves, each wave a 64x64 quadrant (4x4 frags).
//   LDS per K-step: 4 planes x 8KB, k-sliced layout [kgrp][row][8] so the
//   per-lane ds_read_b128 fragment reads are contiguous (conflict-free).
//   Staging via global_load_lds(16B): LDS dest linear, global source
//   pre-permuted to match the k-sliced layout (m173 pattern).
// ==================================================================
__global__ __launch_bounds__(256, 2)
void gemm_bf16x3(const ushort* __restrict__ Ah, const ushort* __restrict__ Al,
                 const ushort* __restrict__ Bh, const ushort* __restrict__ Bl,
                 const float* __restrict__ bias,
                 float* __restrict__ C, int ldc, int Nstore, int Kpad)
{
    __shared__ ushort lds[16384];   // 32 KB: [Ah|Al|Bh|Bl] tiles, 8KB each
    const int tid  = threadIdx.x;
    const int wid  = tid >> 6;
    const int lane = tid & 63;
    const int bm0  = blockIdx.x * 128;
    const int bn0  = blockIdx.y * 128;
    const int wm   = wid >> 1;         // wave quadrant row (0..1)
    const int wn   = wid & 1;          // wave quadrant col (0..1)
    const int l15  = lane & 15;
    const int kg   = lane >> 4;        // k-group 0..3

    // staging: 8 instructions x (256 lanes x 16B) = 32KB per K-step.
    // flat byte F = i*4096 + tid*16 ; plane = F>>13 ; chunk=(F&8191)>>4 ;
    // kgrp = chunk>>7 ; row = chunk&127 ; global elem = (r0+row)*Kpad + kgrp*8
    const ushort* gsrc[8];
    {
        const ushort* pb[4] = {Ah, Al, Bh, Bl};
        #pragma unroll
        for (int i = 0; i < 8; ++i) {
            const int F     = i * 4096 + tid * 16;
            const int pl    = F >> 13;
            const int chunk = (F & 8191) >> 4;
            const int kgrp  = chunk >> 7;
            const int row   = chunk & 127;
            const int r0    = (pl < 2) ? bm0 : bn0;
            gsrc[i] = pb[pl] + (size_t)(r0 + row) * Kpad + kgrp * 8;
        }
    }

    f32x4 acc[4][4];
    #pragma unroll
    for (int m = 0; m < 4; ++m)
        #pragma unroll
        for (int n = 0; n < 4; ++n)
            acc[m][n] = (f32x4){0.f, 0.f, 0.f, 0.f};

    // fragment LDS offsets (ushort units); chunk(kgrp,row) lives at kgrp*1024+row*8
    const int aoff = kg * 1024 + (wm * 64 + l15) * 8;           // in Ah plane
    const int boff = 8192 + kg * 1024 + (wn * 64 + l15) * 8;    // in Bh plane

    for (int k0 = 0; k0 < Kpad; k0 += 32) {
        #pragma unroll
        for (int i = 0; i < 8; ++i) {
            __builtin_amdgcn_global_load_lds(
                (const __attribute__((address_space(1))) void*)(gsrc[i] + k0),
                (__attribute__((address_space(3))) void*)(&lds[i * 2048 + wid * 512]),
                16, 0, 0);
        }
        __syncthreads();   // compiler drains vmcnt before barrier -> tiles ready

        bf16x8 aH[4], aL[4], bH[4], bL[4];
        #pragma unroll
        for (int m = 0; m < 4; ++m) {
            aH[m] = *(const bf16x8*)&lds[aoff + m * 128];
            aL[m] = *(const bf16x8*)&lds[4096 + aoff + m * 128];
        }
        #pragma unroll
        for (int n = 0; n < 4; ++n) {
            bH[n] = *(const bf16x8*)&lds[boff + n * 128];
            bL[n] = *(const bf16x8*)&lds[4096 + boff + n * 128];
        }
        #pragma unroll
        for (int m = 0; m < 4; ++m)
            #pragma unroll
            for (int n = 0; n < 4; ++n) {
                acc[m][n] = __builtin_amdgcn_mfma_f32_16x16x32_bf16(aH[m], bH[n], acc[m][n], 0, 0, 0);
                acc[m][n] = __builtin_amdgcn_mfma_f32_16x16x32_bf16(aH[m], bL[n], acc[m][n], 0, 0, 0);
                acc[m][n] = __builtin_amdgcn_mfma_f32_16x16x32_bf16(aL[m], bH[n], acc[m][n], 0, 0, 0);
            }
        __syncthreads();
    }

    // epilogue: C/D mapping col = lane&15, row = (lane>>4)*4 + reg  [m89/m91]
    #pragma unroll
    for (int n = 0; n < 4; ++n) {
        const int col = bn0 + wn * 64 + n * 16 + l15;
        if (col < Nstore) {
            const float bs = bias[col];
            #pragma unroll
            for (int m = 0; m < 4; ++m) {
                const int row = bm0 + wm * 64 + m * 16 + kg * 4;
                #pragma unroll
                for (int r = 0; r < 4; ++r)
                    C[(size_t)(row + r) * ldc + col] = acc[m][n][r] + bs;
            }
        }
    }
}

// ==================================================================
// LayerNorm + ReLU, emitting hi/lo bf16 planes (+ actions, + zero pad)
// one block (256 thr) per row, N = 1024
// ==================================================================
__global__ __launch_bounds__(256)
void ln_relu_split(const float* __restrict__ Y,
                   const float* __restrict__ g, const float* __restrict__ b,
                   ushort* __restrict__ Xh, ushort* __restrict__ Xl, int xstride,
                   const float* __restrict__ actions, int dopad)
{
    __shared__ float red[4];
    const int row = blockIdx.x;
    const int tid = threadIdx.x;
    const float* y = Y + (size_t)row * 1024;

    const float4 v = *(const float4*)(y + tid * 4);
    float s = v.x + v.y + v.z + v.w;
    #pragma unroll
    for (int off = 32; off > 0; off >>= 1) s += __shfl_down(s, off, 64);
    if ((tid & 63) == 0) red[tid >> 6] = s;
    __syncthreads();
    const float mu = (red[0] + red[1] + red[2] + red[3]) * (1.f / 1024.f);
    __syncthreads();
    const float d0 = v.x - mu, d1 = v.y - mu, d2 = v.z - mu, d3 = v.w - mu;
    float s2 = d0 * d0 + d1 * d1 + d2 * d2 + d3 * d3;
    #pragma unroll
    for (int off = 32; off > 0; off >>= 1) s2 += __shfl_down(s2, off, 64);
    if ((tid & 63) == 0) red[tid >> 6] = s2;
    __syncthreads();
    const float var = (red[0] + red[1] + red[2] + red[3]) * (1.f / 1024.f);
    const float inv = 1.0f / sqrtf(var + LN_EPS_F);

    float o0 = fmaxf(0.f, d0 * inv * g[tid * 4 + 0] + b[tid * 4 + 0]);
    float o1 = fmaxf(0.f, d1 * inv * g[tid * 4 + 1] + b[tid * 4 + 1]);
    float o2 = fmaxf(0.f, d2 * inv * g[tid * 4 + 2] + b[tid * 4 + 2]);
    float o3 = fmaxf(0.f, d3 * inv * g[tid * 4 + 3] + b[tid * 4 + 3]);

    ushort4 oh, ol;
    oh.x = f2bf(o0); ol.x = f2bf(o0 - bf2f(oh.x));
    oh.y = f2bf(o1); ol.y = f2bf(o1 - bf2f(oh.y));
    oh.z = f2bf(o2); ol.z = f2bf(o2 - bf2f(oh.z));
    oh.w = f2bf(o3); ol.w = f2bf(o3 - bf2f(oh.w));
    *(ushort4*)(Xh + (size_t)row * xstride + tid * 4) = oh;
    *(ushort4*)(Xl + (size_t)row * xstride + tid * 4) = ol;

    if (actions != nullptr && tid < 16) {
        const float a = actions[(size_t)row * 16 + tid];
        const ushort h = f2bf(a);
        Xh[(size_t)row * xstride + 1024 + tid] = h;
        Xl[(size_t)row * xstride + 1024 + tid] = f2bf(a - bf2f(h));
    }
    if (dopad && tid >= 16 && tid < 64) {   // zero cols 1040..1087
        Xh[(size_t)row * xstride + 1024 + tid] = 0;
        Xl[(size_t)row * xstride + 1024 + tid] = 0;
    }
}

// ---------------- fp32 matrix -> hi/lo bf16 planes (with K padding) ---------
__global__ __launch_bounds__(256)
void split_mat(const float* __restrict__ src, int scols,
               ushort* __restrict__ Dh, ushort* __restrict__ Dl,
               int dcols, int total)
{
    const int idx = blockIdx.x * 256 + threadIdx.x;
    if (idx >= total) return;
    const int r = idx / dcols, c = idx % dcols;
    const float v = (c < scols) ? src[(size_t)r * scols + c] : 0.f;
    const ushort h = f2bf(v);
    Dh[idx] = h;
    Dl[idx] = f2bf(v - bf2f(h));
}

// ---------------- concatenated head weight [wv; wa; wb; 0pad] -> planes -----
__global__ __launch_bounds__(256)
void build_wcat_split(const float* __restrict__ wv, const float* __restrict__ wa,
                      const float* __restrict__ wb, const float* __restrict__ bv,
                      const float* __restrict__ ba, const float* __restrict__ bb,
                      ushort* __restrict__ Wh, ushort* __restrict__ Wl,
                      float* __restrict__ bcat)
{
    const int idx = blockIdx.x * 256 + threadIdx.x;
    if (idx < 512 * 1024) {
        const int n = idx >> 10, k = idx & 1023;
        const float v = (n < 383) ? wv[n * 1024 + k]
                       : (n == 383) ? wa[k]
                       : (n == 384) ? wb[k] : 0.f;
        const ushort h = f2bf(v);
        Wh[idx] = h;
        Wl[idx] = f2bf(v - bf2f(h));
    }
    if (idx < 512) {
        bcat[idx] = (idx < 383) ? bv[idx] : (idx == 383) ? ba[0]
                   : (idx == 384) ? bb[0] : 0.f;
    }
}

// ==================================================================
// spline: one WAVE per row (4 rows / 256-thr block). Shuffle-based
// softmax + scan, LDS tables per row, 7-step binary search per tau.
// ==================================================================
__device__ __forceinline__ float softplus_f(float x) {
    return (x > 20.f) ? x : log1pf(expf(x));
}

__global__ __launch_bounds__(256)
void spline_rq(const float* __restrict__ P, float* __restrict__ Out)
{
    __shared__ float cw[4][132];
    __shared__ float ch[4][132];
    __shared__ float Dv[4][132];
    const int wid  = threadIdx.x >> 6;
    const int lane = threadIdx.x & 63;
    const int r    = blockIdx.x * 4 + wid;
    const float* p = P + (size_t)r * 385;
    const int e0 = 2 * lane, e1 = 2 * lane + 1;

    const float sa = expf(p[383]);
    const float sb = p[384];

    // ---- W: softmax + affine + pair-scan -> cw[0..128] ----
    const float w0 = p[e0], w1 = p[e1];
    float mx = fmaxf(w0, w1);
    #pragma unroll
    for (int off = 1; off < 64; off <<= 1) mx = fmaxf(mx, __shfl_xor(mx, off, 64));
    const float xw0 = expf(w0 - mx), xw1 = expf(w1 - mx);
    float sw = xw0 + xw1;
    #pragma unroll
    for (int off = 1; off < 64; off <<= 1) sw += __shfl_xor(sw, off, 64);
    const float cwn = (1.f - MINW * 128.f) / sw;
    const float Wv0 = MINW + cwn * xw0;
    const float Wv1 = MINW + cwn * xw1;
    float s = Wv0 + Wv1;
    #pragma unroll
    for (int off = 1; off < 64; off <<= 1) {
        const float t = __shfl_up(s, off, 64);
        if (lane >= off) s += t;
    }
    if (lane == 0) cw[wid][0] = 0.f;
    cw[wid][e1]     = s - Wv1;
    cw[wid][e1 + 1] = (lane == 63) ? 1.0f : s;

    // ---- H: softmax + affine + pair-scan -> ch[0..128] (scaled) ----
    const float h0 = p[128 + e0], h1 = p[128 + e1];
    float mh = fmaxf(h0, h1);
    #pragma unroll
    for (int off = 1; off < 64; off <<= 1) mh = fmaxf(mh, __shfl_xor(mh, off, 64));
    const float xh0 = expf(h0 - mh), xh1 = expf(h1 - mh);
    float sh = xh0 + xh1;
    #pragma unroll
    for (int off = 1; off < 64; off <<= 1) sh += __shfl_xor(sh, off, 64);
    const float chn = (1.f - MINH * 128.f) / sh;
    const float Hv0 = MINH + chn * xh0;
    const float Hv1 = MINH + chn * xh1;
    float t2 = Hv0 + Hv1;
    #pragma unroll
    for (int off = 1; off < 64; off <<= 1) {
        const float t = __shfl_up(t2, off, 64);
        if (lane >= off) t2 += t;
    }
    if (lane == 0) ch[wid][0] = sb;
    ch[wid][e1]     = sa * (t2 - Hv1) + sb;
    ch[wid][e1 + 1] = sa * t2 + sb;

    // ---- derivatives D[0..128] ----
    if (lane == 0) { Dv[wid][0] = EDGE_CONST_F; Dv[wid][128] = EDGE_CONST_F; }
    Dv[wid][e0 + 1] = MIND + softplus_f(p[256 + e0]);           // e0 <= 126
    if (lane < 63) Dv[wid][e1 + 1] = MIND + softplus_f(p[256 + e1]);

    __syncthreads();   // cheap; guarantees LDS visibility before gathers

    // ---- evaluate 2 taus per lane ----
    #pragma unroll
    for (int t = 0; t < 2; ++t) {
        const int e = 2 * lane + t;
        const float tau = ((float)e + 0.5f) * (1.f / 128.f);
        int lo = 0, hi = 128;                 // cw[lo] <= tau < cw[hi]
        #pragma unroll
        for (int it = 0; it < 7; ++it) {
            const int mid = (lo + hi) >> 1;
            if (cw[wid][mid] <= tau) lo = mid; else hi = mid;
        }
        const int bin = lo;
        const float icw = cw[wid][bin];
        const float ibw = cw[wid][bin + 1] - icw;
        const float ich = ch[wid][bin];
        const float ih  = ch[wid][bin + 1] - ich;
        const float idelta = ih / ibw;
        const float dd0 = Dv[wid][bin];
        const float dd1 = Dv[wid][bin + 1];
        const float theta = (tau - icw) / ibw;
        const float tom = theta * (1.f - theta);
        const float num = ih * (idelta * theta * theta + dd0 * tom);
        const float den = idelta + (dd0 + dd1 - 2.f * idelta) * tom;
        Out[(size_t)r * 128 + e] = ich + num / den;
    }
}

// ==================================================================
extern "C" void kernel_launch(void* const* d_in, const int* in_sizes, int n_in,
                              void* d_out, int out_size, void* d_ws, size_t ws_size,
                              hipStream_t stream) {
    const float* inputs  = (const float*)d_in[0];
    const float* actions = (const float*)d_in[1];
    const float* w1      = (const float*)d_in[2];
    const float* b1      = (const float*)d_in[3];
    const float* ln1_g   = (const float*)d_in[4];
    const float* ln1_b   = (const float*)d_in[5];
    const float* w2      = (const float*)d_in[6];
    const float* b2      = (const float*)d_in[7];
    const float* ln2_g   = (const float*)d_in[8];
    const float* ln2_b   = (const float*)d_in[9];
    const float* wv      = (const float*)d_in[10];
    const float* bv      = (const float*)d_in[11];
    const float* wa      = (const float*)d_in[12];
    const float* ba      = (const float*)d_in[13];
    const float* wb      = (const float*)d_in[14];
    const float* bb      = (const float*)d_in[15];

    // ---- workspace layout (146 MB total) ----
    float*  ws_y  = (float*)d_ws;                              // [16384][1024] f32; later params [16384][385]
    ushort* ws_Xh = (ushort*)(ws_y + (size_t)16384 * 1024);    // [16384][1088] bf16 hi (A1/X2/X3 alias)
    ushort* ws_Xl = ws_Xh + (size_t)16384 * 1088;              // lo plane
    ushort* w1h   = ws_Xl + (size_t)16384 * 1088;
    ushort* w1l   = w1h + 1024 * 256;
    ushort* w2h   = w1l + 1024 * 256;
    ushort* w2l   = w2h + 1024 * 1088;
    ushort* wch   = w2l + 1024 * 1088;
    ushort* wcl   = wch + 512 * 1024;
    float*  bcat  = (float*)(wcl + 512 * 1024);

    // ---- weight / input conversion to hi/lo planes ----
    split_mat<<<(16384 * 256 + 255) / 256, 256, 0, stream>>>(inputs, 256, ws_Xh, ws_Xl, 256, 16384 * 256);
    split_mat<<<(1024 * 256 + 255) / 256, 256, 0, stream>>>(w1, 256, w1h, w1l, 256, 1024 * 256);
    split_mat<<<(1024 * 1088 + 255) / 256, 256, 0, stream>>>(w2, 1040, w2h, w2l, 1088, 1024 * 1088);
    build_wcat_split<<<(512 * 1024 + 255) / 256, 256, 0, stream>>>(wv, wa, wb, bv, ba, bb, wch, wcl, bcat);

    // ---- layer 1 ----
    gemm_bf16x3<<<dim3(128, 8), 256, 0, stream>>>(ws_Xh, ws_Xl, w1h, w1l, b1, ws_y, 1024, 1024, 256);
    ln_relu_split<<<16384, 256, 0, stream>>>(ws_y, ln1_g, ln1_b, ws_Xh, ws_Xl, 1088, actions, 1);

    // ---- layer 2 (K padded 1040 -> 1088 with zeros) ----
    gemm_bf16x3<<<dim3(128, 8), 256, 0, stream>>>(ws_Xh, ws_Xl, w2h, w2l, b2, ws_y, 1024, 1024, 1088);
    ln_relu_split<<<16384, 256, 0, stream>>>(ws_y, ln2_g, ln2_b, ws_Xh, ws_Xl, 1024, nullptr, 0);

    // ---- head GEMM (N=512 padded, store 385 cols) -> params in ws_y ----
    gemm_bf16x3<<<dim3(128, 4), 256, 0, stream>>>(ws_Xh, ws_Xl, wch, wcl, bcat, ws_y, 385, 385, 1024);

    // ---- spline ----
    spline_rq<<<4096, 256, 0, stream>>>(ws_y, (float*)d_out);
}

// Round 3
// 451.587 us; speedup vs baseline: 2.0191x; 1.0837x over previous
//
#include <hip/hip_runtime.h>
#include <hip/hip_bf16.h>
#include <math.h>

// ---------------- problem constants ----------------
#define BROWS      16384
#define LN_EPS_F   1e-5f
#define MINW       0.001f
#define MINH       0.001f
#define MIND       0.001f
// float(np.log(np.exp(0.999) - 1.0))
#define EDGE_CONST_F 0.5397423505783211f

typedef __bf16 bf16x8 __attribute__((ext_vector_type(8)));
typedef float  f32x4  __attribute__((ext_vector_type(4)));

// fp32 -> bf16 RNE, and back, via bit ops
__device__ __forceinline__ ushort f2bf(float x) {
    union { float f; unsigned u; } v; v.f = x;
    unsigned u = v.u;
    u += 0x7fffu + ((u >> 16) & 1u);
    return (ushort)(u >> 16);
}
__device__ __forceinline__ float bf2f(ushort h) {
    union { unsigned u; float f; } v; v.u = ((unsigned)h) << 16;
    return v.f;
}

// ==================================================================
// MFMA GEMM, split-precision bf16x3, 2-phase double-buffered pipeline.
//   C = A @ B^T + bias ; A/B given as hi/lo bf16 planes [rows][Kpad].
//   128x128 tile, BK=32, 4 waves (64x64 quadrant each, 4x4 frags).
//   LDS: 2 buffers x 32KB. Per K-step: issue next tile's
//   global_load_lds FIRST, then ds_read+MFMA current, then ONE
//   __syncthreads() (its implicit vmcnt(0) waits on loads that had the
//   whole MFMA phase to land). k-sliced layout [kgrp][row][8] keeps
//   fragment ds_read_b128s conflict-free (verified r2: conflicts = 0).
// ==================================================================
__global__ __launch_bounds__(256, 2)
void gemm_bf16x3(const ushort* __restrict__ Ah, const ushort* __restrict__ Al,
                 const ushort* __restrict__ Bh, const ushort* __restrict__ Bl,
                 const float* __restrict__ bias,
                 float* __restrict__ C, int ldc, int Nstore, int Kpad)
{
    __shared__ ushort lds[32768];   // 64 KB: two [Ah|Al|Bh|Bl] tile buffers
    const int tid  = threadIdx.x;
    const int wid  = tid >> 6;
    const int lane = tid & 63;
    const int bm0  = blockIdx.x * 128;
    const int bn0  = blockIdx.y * 128;
    const int wm   = wid >> 1;
    const int wn   = wid & 1;
    const int l15  = lane & 15;
    const int kg   = lane >> 4;

    // staging source addresses (k-sliced pre-permuted global, m173 pattern)
    // flat byte F = i*4096 + tid*16 ; plane=F>>13 ; chunk=(F&8191)>>4 ;
    // kgrp=chunk>>7 ; row=chunk&127 ; elem = (r0+row)*Kpad + kgrp*8
    const ushort* gsrc[8];
    {
        const ushort* pb[4] = {Ah, Al, Bh, Bl};
        #pragma unroll
        for (int i = 0; i < 8; ++i) {
            const int F     = i * 4096 + tid * 16;
            const int pl    = F >> 13;
            const int chunk = (F & 8191) >> 4;
            const int kgrp  = chunk >> 7;
            const int row   = chunk & 127;
            const int r0    = (pl < 2) ? bm0 : bn0;
            gsrc[i] = pb[pl] + (size_t)(r0 + row) * Kpad + kgrp * 8;
        }
    }
    // per-wave LDS destinations are wave-uniform; HW adds lane*16B
    #define STAGE(bufbase, kelem)                                              \
        _Pragma("unroll")                                                      \
        for (int i = 0; i < 8; ++i) {                                          \
            __builtin_amdgcn_global_load_lds(                                  \
                (const __attribute__((address_space(1))) void*)(gsrc[i] + (kelem)), \
                (__attribute__((address_space(3))) void*)(&lds[(bufbase) + i * 2048 + wid * 512]), \
                16, 0, 0);                                                     \
        }

    f32x4 acc[4][4];
    #pragma unroll
    for (int m = 0; m < 4; ++m)
        #pragma unroll
        for (int n = 0; n < 4; ++n)
            acc[m][n] = (f32x4){0.f, 0.f, 0.f, 0.f};

    const int aoff = kg * 1024 + (wm * 64 + l15) * 8;           // Ah plane
    const int boff = 8192 + kg * 1024 + (wn * 64 + l15) * 8;    // Bh plane
    const int nt = Kpad >> 5;

    STAGE(0, 0);
    __syncthreads();            // implicit vmcnt(0): buf0 ready
    int cur = 0;

    for (int t = 0; t < nt; ++t) {
        const int nxt = cur ^ 1;
        if (t + 1 < nt) STAGE(nxt * 16384, (t + 1) * 32);   // prefetch ahead

        const int cb = cur * 16384;
        bf16x8 aH[4], aL[4], bH[4], bL[4];
        #pragma unroll
        for (int m = 0; m < 4; ++m) {
            aH[m] = *(const bf16x8*)&lds[cb + aoff + m * 128];
            aL[m] = *(const bf16x8*)&lds[cb + 4096 + aoff + m * 128];
        }
        #pragma unroll
        for (int n = 0; n < 4; ++n) {
            bH[n] = *(const bf16x8*)&lds[cb + boff + n * 128];
            bL[n] = *(const bf16x8*)&lds[cb + 4096 + boff + n * 128];
        }

        __builtin_amdgcn_s_setprio(1);
        // three passes: same-acc dependency distance = 16 MFMAs
        #pragma unroll
        for (int m = 0; m < 4; ++m)
            #pragma unroll
            for (int n = 0; n < 4; ++n)
                acc[m][n] = __builtin_amdgcn_mfma_f32_16x16x32_bf16(aH[m], bH[n], acc[m][n], 0, 0, 0);
        #pragma unroll
        for (int m = 0; m < 4; ++m)
            #pragma unroll
            for (int n = 0; n < 4; ++n)
                acc[m][n] = __builtin_amdgcn_mfma_f32_16x16x32_bf16(aH[m], bL[n], acc[m][n], 0, 0, 0);
        #pragma unroll
        for (int m = 0; m < 4; ++m)
            #pragma unroll
            for (int n = 0; n < 4; ++n)
                acc[m][n] = __builtin_amdgcn_mfma_f32_16x16x32_bf16(aL[m], bH[n], acc[m][n], 0, 0, 0);
        __builtin_amdgcn_s_setprio(0);

        __syncthreads();        // drains my prefetch (vmcnt 0) + all reads done
        cur = nxt;
    }
    #undef STAGE

    // epilogue: C/D mapping col = lane&15, row = (lane>>4)*4 + reg  [m89/m91]
    #pragma unroll
    for (int n = 0; n < 4; ++n) {
        const int col = bn0 + wn * 64 + n * 16 + l15;
        if (col < Nstore) {
            const float bs = bias[col];
            #pragma unroll
            for (int m = 0; m < 4; ++m) {
                const int row = bm0 + wm * 64 + m * 16 + kg * 4;
                #pragma unroll
                for (int r = 0; r < 4; ++r)
                    C[(size_t)(row + r) * ldc + col] = acc[m][n][r] + bs;
            }
        }
    }
}

// ==================================================================
// LayerNorm + ReLU, emitting hi/lo bf16 planes (+ actions, + zero pad)
// ==================================================================
__global__ __launch_bounds__(256)
void ln_relu_split(const float* __restrict__ Y,
                   const float* __restrict__ g, const float* __restrict__ b,
                   ushort* __restrict__ Xh, ushort* __restrict__ Xl, int xstride,
                   const float* __restrict__ actions, int dopad)
{
    __shared__ float red[4];
    const int row = blockIdx.x;
    const int tid = threadIdx.x;
    const float* y = Y + (size_t)row * 1024;

    const float4 v = *(const float4*)(y + tid * 4);
    float s = v.x + v.y + v.z + v.w;
    #pragma unroll
    for (int off = 32; off > 0; off >>= 1) s += __shfl_down(s, off, 64);
    if ((tid & 63) == 0) red[tid >> 6] = s;
    __syncthreads();
    const float mu = (red[0] + red[1] + red[2] + red[3]) * (1.f / 1024.f);
    __syncthreads();
    const float d0 = v.x - mu, d1 = v.y - mu, d2 = v.z - mu, d3 = v.w - mu;
    float s2 = d0 * d0 + d1 * d1 + d2 * d2 + d3 * d3;
    #pragma unroll
    for (int off = 32; off > 0; off >>= 1) s2 += __shfl_down(s2, off, 64);
    if ((tid & 63) == 0) red[tid >> 6] = s2;
    __syncthreads();
    const float var = (red[0] + red[1] + red[2] + red[3]) * (1.f / 1024.f);
    const float inv = 1.0f / sqrtf(var + LN_EPS_F);

    float o0 = fmaxf(0.f, d0 * inv * g[tid * 4 + 0] + b[tid * 4 + 0]);
    float o1 = fmaxf(0.f, d1 * inv * g[tid * 4 + 1] + b[tid * 4 + 1]);
    float o2 = fmaxf(0.f, d2 * inv * g[tid * 4 + 2] + b[tid * 4 + 2]);
    float o3 = fmaxf(0.f, d3 * inv * g[tid * 4 + 3] + b[tid * 4 + 3]);

    ushort4 oh, ol;
    oh.x = f2bf(o0); ol.x = f2bf(o0 - bf2f(oh.x));
    oh.y = f2bf(o1); ol.y = f2bf(o1 - bf2f(oh.y));
    oh.z = f2bf(o2); ol.z = f2bf(o2 - bf2f(oh.z));
    oh.w = f2bf(o3); ol.w = f2bf(o3 - bf2f(oh.w));
    *(ushort4*)(Xh + (size_t)row * xstride + tid * 4) = oh;
    *(ushort4*)(Xl + (size_t)row * xstride + tid * 4) = ol;

    if (actions != nullptr && tid < 16) {
        const float a = actions[(size_t)row * 16 + tid];
        const ushort h = f2bf(a);
        Xh[(size_t)row * xstride + 1024 + tid] = h;
        Xl[(size_t)row * xstride + 1024 + tid] = f2bf(a - bf2f(h));
    }
    if (dopad && tid >= 16 && tid < 64) {   // zero cols 1040..1087
        Xh[(size_t)row * xstride + 1024 + tid] = 0;
        Xl[(size_t)row * xstride + 1024 + tid] = 0;
    }
}

// ---------------- fp32 matrix -> hi/lo bf16 planes (with K padding) ---------
__global__ __launch_bounds__(256)
void split_mat(const float* __restrict__ src, int scols,
               ushort* __restrict__ Dh, ushort* __restrict__ Dl,
               int dcols, int total)
{
    const int idx = blockIdx.x * 256 + threadIdx.x;
    if (idx >= total) return;
    const int r = idx / dcols, c = idx % dcols;
    const float v = (c < scols) ? src[(size_t)r * scols + c] : 0.f;
    const ushort h = f2bf(v);
    Dh[idx] = h;
    Dl[idx] = f2bf(v - bf2f(h));
}

// ---------------- concatenated head weight [wv; wa; wb; 0pad] -> planes -----
__global__ __launch_bounds__(256)
void build_wcat_split(const float* __restrict__ wv, const float* __restrict__ wa,
                      const float* __restrict__ wb, const float* __restrict__ bv,
                      const float* __restrict__ ba, const float* __restrict__ bb,
                      ushort* __restrict__ Wh, ushort* __restrict__ Wl,
                      float* __restrict__ bcat)
{
    const int idx = blockIdx.x * 256 + threadIdx.x;
    if (idx < 512 * 1024) {
        const int n = idx >> 10, k = idx & 1023;
        const float v = (n < 383) ? wv[n * 1024 + k]
                       : (n == 383) ? wa[k]
                       : (n == 384) ? wb[k] : 0.f;
        const ushort h = f2bf(v);
        Wh[idx] = h;
        Wl[idx] = f2bf(v - bf2f(h));
    }
    if (idx < 512) {
        bcat[idx] = (idx < 383) ? bv[idx] : (idx == 383) ? ba[0]
                   : (idx == 384) ? bb[0] : 0.f;
    }
}

// ==================================================================
// spline: one WAVE per row (4 rows / 256-thr block)
// ==================================================================
__device__ __forceinline__ float softplus_f(float x) {
    return (x > 20.f) ? x : log1pf(expf(x));
}

__global__ __launch_bounds__(256)
void spline_rq(const float* __restrict__ P, float* __restrict__ Out)
{
    __shared__ float cw[4][132];
    __shared__ float ch[4][132];
    __shared__ float Dv[4][132];
    const int wid  = threadIdx.x >> 6;
    const int lane = threadIdx.x & 63;
    const int r    = blockIdx.x * 4 + wid;
    const float* p = P + (size_t)r * 385;
    const int e0 = 2 * lane, e1 = 2 * lane + 1;

    const float sa = expf(p[383]);
    const float sb = p[384];

    // ---- W: softmax + affine + pair-scan -> cw[0..128] ----
    const float w0 = p[e0], w1 = p[e1];
    float mx = fmaxf(w0, w1);
    #pragma unroll
    for (int off = 1; off < 64; off <<= 1) mx = fmaxf(mx, __shfl_xor(mx, off, 64));
    const float xw0 = expf(w0 - mx), xw1 = expf(w1 - mx);
    float sw = xw0 + xw1;
    #pragma unroll
    for (int off = 1; off < 64; off <<= 1) sw += __shfl_xor(sw, off, 64);
    const float cwn = (1.f - MINW * 128.f) / sw;
    const float Wv0 = MINW + cwn * xw0;
    const float Wv1 = MINW + cwn * xw1;
    float s = Wv0 + Wv1;
    #pragma unroll
    for (int off = 1; off < 64; off <<= 1) {
        const float t = __shfl_up(s, off, 64);
        if (lane >= off) s += t;
    }
    if (lane == 0) cw[wid][0] = 0.f;
    cw[wid][e1]     = s - Wv1;
    cw[wid][e1 + 1] = (lane == 63) ? 1.0f : s;

    // ---- H: softmax + affine + pair-scan -> ch[0..128] (scaled) ----
    const float h0 = p[128 + e0], h1 = p[128 + e1];
    float mh = fmaxf(h0, h1);
    #pragma unroll
    for (int off = 1; off < 64; off <<= 1) mh = fmaxf(mh, __shfl_xor(mh, off, 64));
    const float xh0 = expf(h0 - mh), xh1 = expf(h1 - mh);
    float sh = xh0 + xh1;
    #pragma unroll
    for (int off = 1; off < 64; off <<= 1) sh += __shfl_xor(sh, off, 64);
    const float chn = (1.f - MINH * 128.f) / sh;
    const float Hv0 = MINH + chn * xh0;
    const float Hv1 = MINH + chn * xh1;
    float t2 = Hv0 + Hv1;
    #pragma unroll
    for (int off = 1; off < 64; off <<= 1) {
        const float t = __shfl_up(t2, off, 64);
        if (lane >= off) t2 += t;
    }
    if (lane == 0) ch[wid][0] = sb;
    ch[wid][e1]     = sa * (t2 - Hv1) + sb;
    ch[wid][e1 + 1] = sa * t2 + sb;

    // ---- derivatives D[0..128] ----
    if (lane == 0) { Dv[wid][0] = EDGE_CONST_F; Dv[wid][128] = EDGE_CONST_F; }
    Dv[wid][e0 + 1] = MIND + softplus_f(p[256 + e0]);
    if (lane < 63) Dv[wid][e1 + 1] = MIND + softplus_f(p[256 + e1]);

    __syncthreads();

    // ---- evaluate 2 taus per lane ----
    #pragma unroll
    for (int t = 0; t < 2; ++t) {
        const int e = 2 * lane + t;
        const float tau = ((float)e + 0.5f) * (1.f / 128.f);
        int lo = 0, hi = 128;
        #pragma unroll
        for (int it = 0; it < 7; ++it) {
            const int mid = (lo + hi) >> 1;
            if (cw[wid][mid] <= tau) lo = mid; else hi = mid;
        }
        const int bin = lo;
        const float icw = cw[wid][bin];
        const float ibw = cw[wid][bin + 1] - icw;
        const float ich = ch[wid][bin];
        const float ih  = ch[wid][bin + 1] - ich;
        const float idelta = ih / ibw;
        const float dd0 = Dv[wid][bin];
        const float dd1 = Dv[wid][bin + 1];
        const float theta = (tau - icw) / ibw;
        const float tom = theta * (1.f - theta);
        const float num = ih * (idelta * theta * theta + dd0 * tom);
        const float den = idelta + (dd0 + dd1 - 2.f * idelta) * tom;
        Out[(size_t)r * 128 + e] = ich + num / den;
    }
}

// ==================================================================
extern "C" void kernel_launch(void* const* d_in, const int* in_sizes, int n_in,
                              void* d_out, int out_size, void* d_ws, size_t ws_size,
                              hipStream_t stream) {
    const float* inputs  = (const float*)d_in[0];
    const float* actions = (const float*)d_in[1];
    const float* w1      = (const float*)d_in[2];
    const float* b1      = (const float*)d_in[3];
    const float* ln1_g   = (const float*)d_in[4];
    const float* ln1_b   = (const float*)d_in[5];
    const float* w2      = (const float*)d_in[6];
    const float* b2      = (const float*)d_in[7];
    const float* ln2_g   = (const float*)d_in[8];
    const float* ln2_b   = (const float*)d_in[9];
    const float* wv      = (const float*)d_in[10];
    const float* bv      = (const float*)d_in[11];
    const float* wa      = (const float*)d_in[12];
    const float* ba      = (const float*)d_in[13];
    const float* wb      = (const float*)d_in[14];
    const float* bb      = (const float*)d_in[15];

    // ---- workspace layout ----
    float*  ws_y  = (float*)d_ws;                              // [16384][1024] f32
    ushort* ws_Xh = (ushort*)(ws_y + (size_t)16384 * 1024);    // [16384][1088] bf16 hi
    ushort* ws_Xl = ws_Xh + (size_t)16384 * 1088;              // lo plane
    ushort* w1h   = ws_Xl + (size_t)16384 * 1088;
    ushort* w1l   = w1h + 1024 * 256;
    ushort* w2h   = w1l + 1024 * 256;
    ushort* w2l   = w2h + 1024 * 1088;
    ushort* wch   = w2l + 1024 * 1088;
    ushort* wcl   = wch + 512 * 1024;
    float*  bcat  = (float*)(wcl + 512 * 1024);

    // ---- weight / input conversion to hi/lo planes ----
    split_mat<<<(16384 * 256 + 255) / 256, 256, 0, stream>>>(inputs, 256, ws_Xh, ws_Xl, 256, 16384 * 256);
    split_mat<<<(1024 * 256 + 255) / 256, 256, 0, stream>>>(w1, 256, w1h, w1l, 256, 1024 * 256);
    split_mat<<<(1024 * 1088 + 255) / 256, 256, 0, stream>>>(w2, 1040, w2h, w2l, 1088, 1024 * 1088);
    build_wcat_split<<<(512 * 1024 + 255) / 256, 256, 0, stream>>>(wv, wa, wb, bv, ba, bb, wch, wcl, bcat);

    // ---- layer 1 ----
    gemm_bf16x3<<<dim3(128, 8), 256, 0, stream>>>(ws_Xh, ws_Xl, w1h, w1l, b1, ws_y, 1024, 1024, 256);
    ln_relu_split<<<16384, 256, 0, stream>>>(ws_y, ln1_g, ln1_b, ws_Xh, ws_Xl, 1088, actions, 1);

    // ---- layer 2 (K padded 1040 -> 1088 with zeros) ----
    gemm_bf16x3<<<dim3(128, 8), 256, 0, stream>>>(ws_Xh, ws_Xl, w2h, w2l, b2, ws_y, 1024, 1024, 1088);
    ln_relu_split<<<16384, 256, 0, stream>>>(ws_y, ln2_g, ln2_b, ws_Xh, ws_Xl, 1024, nullptr, 0);

    // ---- head GEMM (N=512 padded, store 385 cols) -> params in ws_y ----
    gemm_bf16x3<<<dim3(128, 4), 256, 0, stream>>>(ws_Xh, ws_Xl, wch, wcl, bcat, ws_y, 385, 385, 1024);

    // ---- spline ----
    spline_rq<<<4096, 256, 0, stream>>>(ws_y, (float*)d_out);
}

// Round 4
// 432.607 us; speedup vs baseline: 2.1076x; 1.0439x over previous
//
#include <hip/hip_runtime.h>
#include <hip/hip_bf16.h>
#include <math.h>

// ---------------- problem constants ----------------
#define BROWS      16384
#define LN_EPS_F   1e-5f
#define MINW       0.001f
#define MINH       0.001f
#define MIND       0.001f
// float(np.log(np.exp(0.999) - 1.0))
#define EDGE_CONST_F 0.5397423505783211f

typedef __bf16 bf16x8 __attribute__((ext_vector_type(8)));
typedef float  f32x4  __attribute__((ext_vector_type(4)));

// fp32 -> bf16 RNE, and back, via bit ops
__device__ __forceinline__ ushort f2bf(float x) {
    union { float f; unsigned u; } v; v.f = x;
    unsigned u = v.u;
    u += 0x7fffu + ((u >> 16) & 1u);
    return (ushort)(u >> 16);
}
__device__ __forceinline__ float bf2f(ushort h) {
    union { unsigned u; float f; } v; v.u = ((unsigned)h) << 16;
    return v.f;
}

// ==================================================================
// MFMA GEMM, split-precision bf16x3, double-buffered with COUNTED
// vmcnt (T4, m218): tile t+1's global_load_lds stay in flight across
// both barriers; we wait vmcnt(8) (all but the 8 newest) instead of
// draining to 0. Raw s_barrier (no implicit vmcnt-0 drain).
//   B1: after counted wait -> tile t resident for all waves.
//   B2: after lgkmcnt(0)   -> all reads of buf[cur] done; the STAGE
//       that overwrites buf[cur] happens 2 iters later, after B2+B1.
// ==================================================================
__global__ __launch_bounds__(256, 2)
void gemm_bf16x3(const ushort* __restrict__ Ah, const ushort* __restrict__ Al,
                 const ushort* __restrict__ Bh, const ushort* __restrict__ Bl,
                 const float* __restrict__ bias,
                 float* __restrict__ C, int ldc, int Nstore, int Kpad)
{
    __shared__ ushort lds[32768];   // 64 KB: two [Ah|Al|Bh|Bl] tile buffers
    const int tid  = threadIdx.x;
    const int wid  = tid >> 6;
    const int lane = tid & 63;
    const int bm0  = blockIdx.x * 128;
    const int bn0  = blockIdx.y * 128;
    const int wm   = wid >> 1;
    const int wn   = wid & 1;
    const int l15  = lane & 15;
    const int kg   = lane >> 4;

    // staging source addresses (k-sliced pre-permuted global, m173 pattern)
    const ushort* gsrc[8];
    {
        const ushort* pb[4] = {Ah, Al, Bh, Bl};
        #pragma unroll
        for (int i = 0; i < 8; ++i) {
            const int F     = i * 4096 + tid * 16;
            const int pl    = F >> 13;
            const int chunk = (F & 8191) >> 4;
            const int kgrp  = chunk >> 7;
            const int row   = chunk & 127;
            const int r0    = (pl < 2) ? bm0 : bn0;
            gsrc[i] = pb[pl] + (size_t)(r0 + row) * Kpad + kgrp * 8;
        }
    }
    #define STAGE(bufbase, kelem)                                              \
        _Pragma("unroll")                                                      \
        for (int i = 0; i < 8; ++i) {                                          \
            __builtin_amdgcn_global_load_lds(                                  \
                (const __attribute__((address_space(1))) void*)(gsrc[i] + (kelem)), \
                (__attribute__((address_space(3))) void*)(&lds[(bufbase) + i * 2048 + wid * 512]), \
                16, 0, 0);                                                     \
        }

    f32x4 acc[4][4];
    #pragma unroll
    for (int m = 0; m < 4; ++m)
        #pragma unroll
        for (int n = 0; n < 4; ++n)
            acc[m][n] = (f32x4){0.f, 0.f, 0.f, 0.f};

    const int aoff = kg * 1024 + (wm * 64 + l15) * 8;           // Ah plane
    const int boff = 8192 + kg * 1024 + (wn * 64 + l15) * 8;    // Bh plane
    const int nt = Kpad >> 5;

    STAGE(0, 0);
    int cur = 0;

    for (int t = 0; t < nt; ++t) {
        const int nxt = cur ^ 1;
        if (t + 1 < nt) {
            STAGE(nxt * 16384, (t + 1) * 32);       // prefetch stays in flight
            asm volatile("s_waitcnt vmcnt(8)" ::: "memory");  // tile t landed
        } else {
            asm volatile("s_waitcnt vmcnt(0)" ::: "memory");
        }
        __builtin_amdgcn_sched_barrier(0);
        __builtin_amdgcn_s_barrier();               // B1: tile t visible to all
        asm volatile("" ::: "memory");

        const int cb = cur * 16384;
        bf16x8 aH[4], aL[4], bH[4], bL[4];
        #pragma unroll
        for (int m = 0; m < 4; ++m) {
            aH[m] = *(const bf16x8*)&lds[cb + aoff + m * 128];
            aL[m] = *(const bf16x8*)&lds[cb + 4096 + aoff + m * 128];
        }
        #pragma unroll
        for (int n = 0; n < 4; ++n) {
            bH[n] = *(const bf16x8*)&lds[cb + boff + n * 128];
            bL[n] = *(const bf16x8*)&lds[cb + 4096 + boff + n * 128];
        }

        __builtin_amdgcn_s_setprio(1);
        #pragma unroll
        for (int m = 0; m < 4; ++m)
            #pragma unroll
            for (int n = 0; n < 4; ++n)
                acc[m][n] = __builtin_amdgcn_mfma_f32_16x16x32_bf16(aH[m], bH[n], acc[m][n], 0, 0, 0);
        #pragma unroll
        for (int m = 0; m < 4; ++m)
            #pragma unroll
            for (int n = 0; n < 4; ++n)
                acc[m][n] = __builtin_amdgcn_mfma_f32_16x16x32_bf16(aH[m], bL[n], acc[m][n], 0, 0, 0);
        #pragma unroll
        for (int m = 0; m < 4; ++m)
            #pragma unroll
            for (int n = 0; n < 4; ++n)
                acc[m][n] = __builtin_amdgcn_mfma_f32_16x16x32_bf16(aL[m], bH[n], acc[m][n], 0, 0, 0);
        __builtin_amdgcn_s_setprio(0);

        asm volatile("s_waitcnt lgkmcnt(0)" ::: "memory");  // reads done
        __builtin_amdgcn_sched_barrier(0);
        __builtin_amdgcn_s_barrier();               // B2: buf[cur] reusable
        asm volatile("" ::: "memory");
        cur = nxt;
    }
    #undef STAGE

    // epilogue: C/D mapping col = lane&15, row = (lane>>4)*4 + reg  [m89/m91]
    #pragma unroll
    for (int n = 0; n < 4; ++n) {
        const int col = bn0 + wn * 64 + n * 16 + l15;
        if (col < Nstore) {
            const float bs = bias[col];
            #pragma unroll
            for (int m = 0; m < 4; ++m) {
                const int row = bm0 + wm * 64 + m * 16 + kg * 4;
                #pragma unroll
                for (int r = 0; r < 4; ++r)
                    C[(size_t)(row + r) * ldc + col] = acc[m][n][r] + bs;
            }
        }
    }
}

// ==================================================================
// LayerNorm + ReLU, emitting hi/lo bf16 planes (+ actions, + zero pad)
// ==================================================================
__global__ __launch_bounds__(256)
void ln_relu_split(const float* __restrict__ Y,
                   const float* __restrict__ g, const float* __restrict__ b,
                   ushort* __restrict__ Xh, ushort* __restrict__ Xl, int xstride,
                   const float* __restrict__ actions, int dopad)
{
    __shared__ float red[4];
    const int row = blockIdx.x;
    const int tid = threadIdx.x;
    const float* y = Y + (size_t)row * 1024;

    const float4 v = *(const float4*)(y + tid * 4);
    float s = v.x + v.y + v.z + v.w;
    #pragma unroll
    for (int off = 32; off > 0; off >>= 1) s += __shfl_down(s, off, 64);
    if ((tid & 63) == 0) red[tid >> 6] = s;
    __syncthreads();
    const float mu = (red[0] + red[1] + red[2] + red[3]) * (1.f / 1024.f);
    __syncthreads();
    const float d0 = v.x - mu, d1 = v.y - mu, d2 = v.z - mu, d3 = v.w - mu;
    float s2 = d0 * d0 + d1 * d1 + d2 * d2 + d3 * d3;
    #pragma unroll
    for (int off = 32; off > 0; off >>= 1) s2 += __shfl_down(s2, off, 64);
    if ((tid & 63) == 0) red[tid >> 6] = s2;
    __syncthreads();
    const float var = (red[0] + red[1] + red[2] + red[3]) * (1.f / 1024.f);
    const float inv = 1.0f / sqrtf(var + LN_EPS_F);

    float o0 = fmaxf(0.f, d0 * inv * g[tid * 4 + 0] + b[tid * 4 + 0]);
    float o1 = fmaxf(0.f, d1 * inv * g[tid * 4 + 1] + b[tid * 4 + 1]);
    float o2 = fmaxf(0.f, d2 * inv * g[tid * 4 + 2] + b[tid * 4 + 2]);
    float o3 = fmaxf(0.f, d3 * inv * g[tid * 4 + 3] + b[tid * 4 + 3]);

    ushort4 oh, ol;
    oh.x = f2bf(o0); ol.x = f2bf(o0 - bf2f(oh.x));
    oh.y = f2bf(o1); ol.y = f2bf(o1 - bf2f(oh.y));
    oh.z = f2bf(o2); ol.z = f2bf(o2 - bf2f(oh.z));
    oh.w = f2bf(o3); ol.w = f2bf(o3 - bf2f(oh.w));
    *(ushort4*)(Xh + (size_t)row * xstride + tid * 4) = oh;
    *(ushort4*)(Xl + (size_t)row * xstride + tid * 4) = ol;

    if (actions != nullptr && tid < 16) {
        const float a = actions[(size_t)row * 16 + tid];
        const ushort h = f2bf(a);
        Xh[(size_t)row * xstride + 1024 + tid] = h;
        Xl[(size_t)row * xstride + 1024 + tid] = f2bf(a - bf2f(h));
    }
    if (dopad && tid >= 16 && tid < 64) {   // zero cols 1040..1087
        Xh[(size_t)row * xstride + 1024 + tid] = 0;
        Xl[(size_t)row * xstride + 1024 + tid] = 0;
    }
}

// ---------------- fp32 matrix -> hi/lo bf16 planes, 4 elems/thread ----------
// requires scols % 4 == 0 and dcols % 4 == 0 (true for all uses)
__global__ __launch_bounds__(256)
void split_mat(const float* __restrict__ src, int scols,
               ushort* __restrict__ Dh, ushort* __restrict__ Dl,
               int dcols, int total)
{
    const int idx = (blockIdx.x * 256 + threadIdx.x) * 4;
    if (idx >= total) return;
    const int r = idx / dcols, c = idx % dcols;
    float e[4];
    if (c + 3 < scols) {
        const float4 v = *(const float4*)(src + (size_t)r * scols + c);
        e[0] = v.x; e[1] = v.y; e[2] = v.z; e[3] = v.w;
    } else {
        #pragma unroll
        for (int j = 0; j < 4; ++j)
            e[j] = (c + j < scols) ? src[(size_t)r * scols + c + j] : 0.f;
    }
    ushort4 h, l;
    h.x = f2bf(e[0]); l.x = f2bf(e[0] - bf2f(h.x));
    h.y = f2bf(e[1]); l.y = f2bf(e[1] - bf2f(h.y));
    h.z = f2bf(e[2]); l.z = f2bf(e[2] - bf2f(h.z));
    h.w = f2bf(e[3]); l.w = f2bf(e[3] - bf2f(h.w));
    *(ushort4*)(Dh + idx) = h;
    *(ushort4*)(Dl + idx) = l;
}

// ---------------- concatenated head weight [wv; wa; wb; 0pad] -> planes -----
__global__ __launch_bounds__(256)
void build_wcat_split(const float* __restrict__ wv, const float* __restrict__ wa,
                      const float* __restrict__ wb, const float* __restrict__ bv,
                      const float* __restrict__ ba, const float* __restrict__ bb,
                      ushort* __restrict__ Wh, ushort* __restrict__ Wl,
                      float* __restrict__ bcat)
{
    const int idx = blockIdx.x * 256 + threadIdx.x;
    if (idx < 512 * 1024) {
        const int n = idx >> 10, k = idx & 1023;
        const float v = (n < 383) ? wv[n * 1024 + k]
                       : (n == 383) ? wa[k]
                       : (n == 384) ? wb[k] : 0.f;
        const ushort h = f2bf(v);
        Wh[idx] = h;
        Wl[idx] = f2bf(v - bf2f(h));
    }
    if (idx < 512) {
        bcat[idx] = (idx < 383) ? bv[idx] : (idx == 383) ? ba[0]
                   : (idx == 384) ? bb[0] : 0.f;
    }
}

// ==================================================================
// spline: one WAVE per row (4 rows / 256-thr block)
// ==================================================================
__device__ __forceinline__ float softplus_f(float x) {
    return (x > 20.f) ? x : log1pf(expf(x));
}

__global__ __launch_bounds__(256)
void spline_rq(const float* __restrict__ P, float* __restrict__ Out)
{
    __shared__ float cw[4][132];
    __shared__ float ch[4][132];
    __shared__ float Dv[4][132];
    const int wid  = threadIdx.x >> 6;
    const int lane = threadIdx.x & 63;
    const int r    = blockIdx.x * 4 + wid;
    const float* p = P + (size_t)r * 385;
    const int e0 = 2 * lane, e1 = 2 * lane + 1;

    const float sa = expf(p[383]);
    const float sb = p[384];

    // ---- W: softmax + affine + pair-scan -> cw[0..128] ----
    const float w0 = p[e0], w1 = p[e1];
    float mx = fmaxf(w0, w1);
    #pragma unroll
    for (int off = 1; off < 64; off <<= 1) mx = fmaxf(mx, __shfl_xor(mx, off, 64));
    const float xw0 = expf(w0 - mx), xw1 = expf(w1 - mx);
    float sw = xw0 + xw1;
    #pragma unroll
    for (int off = 1; off < 64; off <<= 1) sw += __shfl_xor(sw, off, 64);
    const float cwn = (1.f - MINW * 128.f) / sw;
    const float Wv0 = MINW + cwn * xw0;
    const float Wv1 = MINW + cwn * xw1;
    float s = Wv0 + Wv1;
    #pragma unroll
    for (int off = 1; off < 64; off <<= 1) {
        const float t = __shfl_up(s, off, 64);
        if (lane >= off) s += t;
    }
    if (lane == 0) cw[wid][0] = 0.f;
    cw[wid][e1]     = s - Wv1;
    cw[wid][e1 + 1] = (lane == 63) ? 1.0f : s;

    // ---- H: softmax + affine + pair-scan -> ch[0..128] (scaled) ----
    const float h0 = p[128 + e0], h1 = p[128 + e1];
    float mh = fmaxf(h0, h1);
    #pragma unroll
    for (int off = 1; off < 64; off <<= 1) mh = fmaxf(mh, __shfl_xor(mh, off, 64));
    const float xh0 = expf(h0 - mh), xh1 = expf(h1 - mh);
    float sh = xh0 + xh1;
    #pragma unroll
    for (int off = 1; off < 64; off <<= 1) sh += __shfl_xor(sh, off, 64);
    const float chn = (1.f - MINH * 128.f) / sh;
    const float Hv0 = MINH + chn * xh0;
    const float Hv1 = MINH + chn * xh1;
    float t2 = Hv0 + Hv1;
    #pragma unroll
    for (int off = 1; off < 64; off <<= 1) {
        const float t = __shfl_up(t2, off, 64);
        if (lane >= off) t2 += t;
    }
    if (lane == 0) ch[wid][0] = sb;
    ch[wid][e1]     = sa * (t2 - Hv1) + sb;
    ch[wid][e1 + 1] = sa * t2 + sb;

    // ---- derivatives D[0..128] ----
    if (lane == 0) { Dv[wid][0] = EDGE_CONST_F; Dv[wid][128] = EDGE_CONST_F; }
    Dv[wid][e0 + 1] = MIND + softplus_f(p[256 + e0]);
    if (lane < 63) Dv[wid][e1 + 1] = MIND + softplus_f(p[256 + e1]);

    __syncthreads();

    // ---- evaluate 2 taus per lane ----
    #pragma unroll
    for (int t = 0; t < 2; ++t) {
        const int e = 2 * lane + t;
        const float tau = ((float)e + 0.5f) * (1.f / 128.f);
        int lo = 0, hi = 128;
        #pragma unroll
        for (int it = 0; it < 7; ++it) {
            const int mid = (lo + hi) >> 1;
            if (cw[wid][mid] <= tau) lo = mid; else hi = mid;
        }
        const int bin = lo;
        const float icw = cw[wid][bin];
        const float ibw = cw[wid][bin + 1] - icw;
        const float ich = ch[wid][bin];
        const float ih  = ch[wid][bin + 1] - ich;
        const float idelta = ih / ibw;
        const float dd0 = Dv[wid][bin];
        const float dd1 = Dv[wid][bin + 1];
        const float theta = (tau - icw) / ibw;
        const float tom = theta * (1.f - theta);
        const float num = ih * (idelta * theta * theta + dd0 * tom);
        const float den = idelta + (dd0 + dd1 - 2.f * idelta) * tom;
        Out[(size_t)r * 128 + e] = ich + num / den;
    }
}

// ==================================================================
extern "C" void kernel_launch(void* const* d_in, const int* in_sizes, int n_in,
                              void* d_out, int out_size, void* d_ws, size_t ws_size,
                              hipStream_t stream) {
    const float* inputs  = (const float*)d_in[0];
    const float* actions = (const float*)d_in[1];
    const float* w1      = (const float*)d_in[2];
    const float* b1      = (const float*)d_in[3];
    const float* ln1_g   = (const float*)d_in[4];
    const float* ln1_b   = (const float*)d_in[5];
    const float* w2      = (const float*)d_in[6];
    const float* b2      = (const float*)d_in[7];
    const float* ln2_g   = (const float*)d_in[8];
    const float* ln2_b   = (const float*)d_in[9];
    const float* wv      = (const float*)d_in[10];
    const float* bv      = (const float*)d_in[11];
    const float* wa      = (const float*)d_in[12];
    const float* ba      = (const float*)d_in[13];
    const float* wb      = (const float*)d_in[14];
    const float* bb      = (const float*)d_in[15];

    // ---- workspace layout ----
    float*  ws_y  = (float*)d_ws;                              // [16384][1024] f32
    ushort* ws_Xh = (ushort*)(ws_y + (size_t)16384 * 1024);    // [16384][1088] bf16 hi
    ushort* ws_Xl = ws_Xh + (size_t)16384 * 1088;              // lo plane
    ushort* w1h   = ws_Xl + (size_t)16384 * 1088;
    ushort* w1l   = w1h + 1024 * 256;
    ushort* w2h   = w1l + 1024 * 256;
    ushort* w2l   = w2h + 1024 * 1088;
    ushort* wch   = w2l + 1024 * 1088;
    ushort* wcl   = wch + 512 * 1024;
    float*  bcat  = (float*)(wcl + 512 * 1024);

    // ---- weight / input conversion to hi/lo planes ----
    split_mat<<<(16384 * 256 / 4 + 255) / 256, 256, 0, stream>>>(inputs, 256, ws_Xh, ws_Xl, 256, 16384 * 256);
    split_mat<<<(1024 * 256 / 4 + 255) / 256, 256, 0, stream>>>(w1, 256, w1h, w1l, 256, 1024 * 256);
    split_mat<<<(1024 * 1088 / 4 + 255) / 256, 256, 0, stream>>>(w2, 1040, w2h, w2l, 1088, 1024 * 1088);
    build_wcat_split<<<(512 * 1024 + 255) / 256, 256, 0, stream>>>(wv, wa, wb, bv, ba, bb, wch, wcl, bcat);

    // ---- layer 1 ----
    gemm_bf16x3<<<dim3(128, 8), 256, 0, stream>>>(ws_Xh, ws_Xl, w1h, w1l, b1, ws_y, 1024, 1024, 256);
    ln_relu_split<<<16384, 256, 0, stream>>>(ws_y, ln1_g, ln1_b, ws_Xh, ws_Xl, 1088, actions, 1);

    // ---- layer 2 (K padded 1040 -> 1088 with zeros) ----
    gemm_bf16x3<<<dim3(128, 8), 256, 0, stream>>>(ws_Xh, ws_Xl, w2h, w2l, b2, ws_y, 1024, 1024, 1088);
    ln_relu_split<<<16384, 256, 0, stream>>>(ws_y, ln2_g, ln2_b, ws_Xh, ws_Xl, 1024, nullptr, 0);

    // ---- head GEMM (N=512 padded, store 385 cols) -> params in ws_y ----
    gemm_bf16x3<<<dim3(128, 4), 256, 0, stream>>>(ws_Xh, ws_Xl, wch, wcl, bcat, ws_y, 385, 385, 1024);

    // ---- spline ----
    spline_rq<<<4096, 256, 0, stream>>>(ws_y, (float*)d_out);
}